// Round 2
// baseline (207.910 us; speedup 1.0000x reference)
//
#include <hip/hip_runtime.h>
#include <math.h>

// VQ-VAE VectorQuantizer forward (MFMA bf16-split formulation), round N+2.
// Same math/GATE as prior rounds (bf16-split MFMA fast scan, packed index,
// exact np-order re-resolution of gated points). Changes this round:
//   1. vq_prep grid 8 -> 36 blocks (round-1 regression: 8 CUs busy, ~55us).
//   2. vq_finalize fused into vq_main's last block (device-scope ticket).
//   3. Exact-refine parallelized: gated points -> LDS worklist, 8 lanes per
//      point (one candidate chain each, identical fp32 sequence), lex-min
//      (dist,k) via shfl_xor. Replaces 8x-serial gather-bound per-thread tail.
//   4. Prologue: ecb copy ordered before staging issue so its wait doesn't
//      drain the chunk-0/1 global_load_lds queue.

typedef __attribute__((ext_vector_type(8))) short short8v;
typedef __attribute__((ext_vector_type(4))) float float4v;
typedef unsigned short u16;
typedef unsigned int u32;

constexpr int D = 64;
constexpr int K = 1024;
constexpr int NPTS = 65536;
constexpr long QOFF = (long)NPTS * D;  // 4194304
constexpr float BIAS = 24.0f;
constexpr float GATE = 5e-3f;  // 2*(split 5e-4 + pack 1e-3) + ref err 2e-4 + margin

// ws layout (16B-aligned sections):
constexpr size_t OFF_LOSS = 0;                               // double
constexpr size_t OFF_DONE = 16;                              // int ticket
constexpr size_t OFF_CNT  = 256;                             // int[1024]
constexpr size_t OFF_EC   = OFF_CNT + 4096;                  // float[1024] ref-order norms
constexpr size_t OFF_ECB  = OFF_EC + 4096;                   // float[1024] norms + BIAS
constexpr size_t OFF_ET   = OFF_ECB + 4096;                  // float[1024*64] E transposed [k][d]
constexpr size_t OFF_STG  = OFF_ET + (size_t)K * D * 4;      // 256KB pre-swizzled staging image

__device__ __forceinline__ float med3(float a, float b, float c) {
  return __builtin_amdgcn_fmed3f(a, b, c);
}
__device__ __forceinline__ u16 bf16rtn(float x) {
  u32 u = __float_as_uint(x);
  return (u16)((u + 0x7fffu + ((u >> 16) & 1u)) >> 16);
}
__device__ __forceinline__ float bf2f(u16 h) {
  return __uint_as_float(((u32)h) << 16);
}
// async global->LDS, 16B per lane; dest must be wave-uniform base + lane*16.
__device__ __forceinline__ void gl_lds16(const void* g, void* l) {
  __builtin_amdgcn_global_load_lds(
      (const __attribute__((address_space(1))) u32*)g,
      (__attribute__((address_space(3))) u32*)l, 16, 0, 0);
}

// ---------------------------------------------------------------------------
// Prep, grid 36 x 256:
//   blocks 0..31 (8192 threads): thread <-> (k, d-group g of 8): Et rows +
//     pre-swizzled -2E bf16 hi/lo staging image.
//   blocks 32..35 (1024 threads): thread <-> k: ref-order ||e_k||^2 (exact
//     sequential fp32 over d ascending), eCb, counts/loss/ticket zeroing.
// Staging image layout (matches vq_main's LDS image; staging = contiguous
// 16B-granular copy): chunk = k>>7, r = k&127, 256B rows:
//   bytes [0,128): hi bf16 16B unit at (s*64+q*16) ^ ((r&7)*16); [128,256): lo
//   d = s*32 + q*8 + j  (A-fragment convention of mfma_f32_16x16x32_bf16)
__global__ __launch_bounds__(256) void vq_prep(const float* __restrict__ E,
                                               float* __restrict__ eC,
                                               float* __restrict__ eCb,
                                               float* __restrict__ Et,
                                               unsigned char* __restrict__ stg,
                                               double* __restrict__ lossSum,
                                               int* __restrict__ counts,
                                               int* __restrict__ done) {
  const int b = blockIdx.x;
  const int tid = threadIdx.x;
  if (b < 32) {
    int gid = b * 256 + tid;
    int k = gid & 1023;        // block covers 256 consecutive k -> coalesced
    int g = gid >> 10;         // d-group 0..7, d = g*8 + j
    float v[8];
#pragma unroll
    for (int j = 0; j < 8; ++j) v[j] = E[(g * 8 + j) * K + k];
    *(float4*)&Et[(size_t)k * 64 + g * 8] = make_float4(v[0], v[1], v[2], v[3]);
    *(float4*)&Et[(size_t)k * 64 + g * 8 + 4] = make_float4(v[4], v[5], v[6], v[7]);
    short8v hv, lv;
#pragma unroll
    for (int j = 0; j < 8; ++j) {
      float m2 = -2.0f * v[j];  // exact
      u16 h = bf16rtn(m2);
      hv[j] = (short)h;
      lv[j] = (short)bf16rtn(m2 - bf2f(h));
    }
    size_t rowb = (size_t)(k >> 7) * 32768 + (size_t)(k & 127) * 256;
    int s = g >> 2, q = g & 3;  // s*32 + q*8 == g*8
    int off = (s * 64 + q * 16) ^ ((k & 7) * 16);
    *(short8v*)&stg[rowb + off] = hv;
    *(short8v*)&stg[rowb + 128 + off] = lv;
  } else {
    int k = (b - 32) * 256 + tid;  // 0..1023
    float c = __fmul_rn(E[k], E[k]);
#pragma unroll
    for (int d = 1; d < D; ++d) {
      float vv = E[d * K + k];
      c = __fadd_rn(c, __fmul_rn(vv, vv));
    }
    eC[k] = c;
    eCb[k] = c + BIAS;
    counts[k] = 0;
    if (k == 0) { *lossSum = 0.0; *done = 0; }
  }
}

// ---------------------------------------------------------------------------
__global__ __launch_bounds__(256) void vq_main(const float* __restrict__ x,
                                               const unsigned char* __restrict__ stg,
                                               const float* __restrict__ eC,
                                               const float* __restrict__ eCb,
                                               const float* __restrict__ Etg,
                                               float* __restrict__ out,
                                               double* __restrict__ lossSum,
                                               int* __restrict__ counts,
                                               int* __restrict__ done) {
  // LDS ~78.6KB -> 2 blocks/CU (grid 512 = 2/CU).
  __shared__ __align__(16) unsigned char sbuf[2][32768];
  __shared__ __align__(16) float ecb[1024];
  __shared__ __align__(16) float topbuf[256 * 4];
  __shared__ int bkbuf[128];
  __shared__ int gks[128 * 8];   // candidate code ids for gated points
  __shared__ short glist[128];   // gated point ids
  __shared__ int gcnt;
  __shared__ int lastFlag;

  const int tid = threadIdx.x;
  const int w = tid >> 6;        // wave id: owns point-tiles 2w, 2w+1
  const int lane = tid & 63;
  const int col = lane & 15;     // A: code row; B/C: point col
  const int quad = lane >> 4;    // k-group (A/B), row-group (C)
  const int blockBase = blockIdx.x * 128;
  const float INF = __builtin_inff();

  // ---- phase 0: biased norms -> LDS (before staging issue: its implicit
  // vmcnt wait then doesn't drain the global_load_lds queue) ----
  *(float4*)&ecb[tid * 4] = *(const float4*)&eCb[tid * 4];
  if (tid == 0) gcnt = 0;

  // ---- phase 1: load + split x into B-fragments (register-resident) ----
  short8v Bh[2][2], Bl[2][2];
#pragma unroll
  for (int pt = 0; pt < 2; ++pt) {
    const float* xp = x + (size_t)(blockBase + w * 32 + pt * 16 + col) * 64;
#pragma unroll
    for (int s = 0; s < 2; ++s) {
      const float4* src = (const float4*)(xp + s * 32 + quad * 8);
      float4 a = src[0], b = src[1];
      float xs[8] = {a.x, a.y, a.z, a.w, b.x, b.y, b.z, b.w};
      short8v hf, lf;
#pragma unroll
      for (int j = 0; j < 8; ++j) {
        u16 h = bf16rtn(xs[j]);
        hf[j] = (short)h;
        lf[j] = (short)bf16rtn(xs[j] - bf2f(h));
      }
      Bh[pt][s] = hf;
      Bl[pt][s] = lf;
    }
  }
  __builtin_amdgcn_sched_barrier(0);

  // ---- prologue: stage chunks 0 and 1 (8 x 16B per thread per chunk) ----
  {
    const unsigned char* s0 = stg + (size_t)tid * 16;
#pragma unroll
    for (int i = 0; i < 8; ++i)
      gl_lds16(s0 + i * 4096, &sbuf[0][tid * 16 + i * 4096]);
#pragma unroll
    for (int i = 0; i < 8; ++i)
      gl_lds16(s0 + 32768 + i * 4096, &sbuf[1][tid * 16 + i * 4096]);
  }
  // wait chunk0 (8 newest = chunk1 stay in flight); ecb ds_writes visible.
  asm volatile("s_waitcnt vmcnt(8) lgkmcnt(0)" ::: "memory");
  __builtin_amdgcn_s_barrier();
  __builtin_amdgcn_sched_barrier(0);
  asm volatile("" ::: "memory");

  // running top-2 of packed biased distances, per point-tile
  float b1[2] = {INF, INF}, b2[2] = {INF, INF};
  const int swz = (col & 7) * 16;  // read-side XOR swizzle (row&7 == col&7)

  // ---- phase 2: K loop, 8 chunks of 128 codes, double-buffered ----
#pragma unroll 1
  for (int ch = 0; ch < 8; ++ch) {
    unsigned char* bufB = sbuf[ch & 1];
#pragma unroll
    for (int ct = 0; ct < 8; ++ct) {  // 8 code-tiles of 16
      const int rb = ct * 4096 + col * 256;  // row = ct*16+col, 256B rows
      short8v Ah0 = *(const short8v*)&bufB[rb + ((quad * 16) ^ swz)];
      short8v Ah1 = *(const short8v*)&bufB[rb + ((64 + quad * 16) ^ swz)];
      short8v Al0 = *(const short8v*)&bufB[rb + 128 + ((quad * 16) ^ swz)];
      short8v Al1 = *(const short8v*)&bufB[rb + 128 + ((64 + quad * 16) ^ swz)];
      float4v Ci = *(const float4v*)&ecb[ch * 128 + ct * 16 + quad * 4];
#pragma unroll
      for (int pt = 0; pt < 2; ++pt) {
        // split accumulators: two independent 3-deep MFMA chains per pt
        float4v Ca = Ci;
        float4v Cb = {0.f, 0.f, 0.f, 0.f};
        Ca = __builtin_amdgcn_mfma_f32_16x16x32_bf16(Ah0, Bh[pt][0], Ca, 0, 0, 0);
        Cb = __builtin_amdgcn_mfma_f32_16x16x32_bf16(Ah1, Bh[pt][1], Cb, 0, 0, 0);
        Ca = __builtin_amdgcn_mfma_f32_16x16x32_bf16(Al0, Bh[pt][0], Ca, 0, 0, 0);
        Cb = __builtin_amdgcn_mfma_f32_16x16x32_bf16(Al1, Bh[pt][1], Cb, 0, 0, 0);
        Ca = __builtin_amdgcn_mfma_f32_16x16x32_bf16(Ah0, Bl[pt][0], Ca, 0, 0, 0);
        Cb = __builtin_amdgcn_mfma_f32_16x16x32_bf16(Ah1, Bl[pt][1], Cb, 0, 0, 0);
#pragma unroll
        for (int r = 0; r < 4; ++r) {
          float dv = Ca[r] + Cb[r];
          // pack local id (ch:3b | ct:3b | r:2b) into low 8 mantissa bits
          u32 u = (__float_as_uint(dv) & 0xffffff00u) |
                  (u32)(ch * 32 + ct * 4 + r);
          float v = __uint_as_float(u);
          float pb = b1[pt];
          b1[pt] = fminf(pb, v);
          b2[pt] = med3(pb, b2[pt], v);
        }
      }
    }
    // barrier #1: my LDS reads of bufB delivered; everyone done with bufB.
    asm volatile("s_waitcnt lgkmcnt(0)" ::: "memory");
    __builtin_amdgcn_s_barrier();
    __builtin_amdgcn_sched_barrier(0);
    asm volatile("" ::: "memory");
    if (ch < 6) {
      // overwrite bufB with chunk ch+2; chunk ch+1's 8 loads stay in flight.
      const unsigned char* s2 = stg + (size_t)(ch + 2) * 32768 + (size_t)tid * 16;
#pragma unroll
      for (int i = 0; i < 8; ++i)
        gl_lds16(s2 + i * 4096, &bufB[tid * 16 + i * 4096]);
      asm volatile("s_waitcnt vmcnt(8)" ::: "memory");  // ch+1 done, ch+2 in flight
    } else if (ch == 6) {
      asm volatile("s_waitcnt vmcnt(0)" ::: "memory");  // last chunk (7) done
    }
    if (ch < 7) {
      // barrier #2: every wave has confirmed its share of chunk ch+1 landed.
      __builtin_amdgcn_s_barrier();
      __builtin_amdgcn_sched_barrier(0);
      asm volatile("" ::: "memory");
    }
  }

  // ---- phase 3: stash per-lane top-2, merge per point, build gated list ----
  topbuf[tid * 4 + 0] = b1[0];
  topbuf[tid * 4 + 1] = b2[0];
  topbuf[tid * 4 + 2] = b1[1];
  topbuf[tid * 4 + 3] = b2[1];
  __syncthreads();

  if (tid < 128) {  // one thread per point; tid == point-in-block by construction
    const int mw = tid >> 5, mpt = (tid >> 4) & 1, mcol = tid & 15;
    float cv[8];
    int cq[8];
    float mv0 = INF, mv1 = INF;
    int q0 = 0;
#pragma unroll
    for (int q = 0; q < 4; ++q) {
      int lbase = (mw * 64 + q * 16 + mcol) * 4 + mpt * 2;
#pragma unroll
      for (int j = 0; j < 2; ++j) {
        float v = topbuf[lbase + j];
        cv[q * 2 + j] = v;
        cq[q * 2 + j] = q;
        if (v < mv0) { mv1 = mv0; mv0 = v; q0 = q; }
        else if (v < mv1) { mv1 = v; }
      }
    }
    u32 lb = __float_as_uint(mv0) & 255u;
    int bestk = (int)((lb >> 5) * 128 + ((lb >> 2) & 7) * 16 + q0 * 4 + (lb & 3));

    if (mv1 - mv0 < GATE) {
      // defer to the parallel exact pass: record point + its 8 candidate ks
      int idx = atomicAdd(&gcnt, 1);
      glist[idx] = (short)tid;
#pragma unroll
      for (int c = 0; c < 8; ++c) {
        u32 cb = __float_as_uint(cv[c]) & 255u;
        gks[idx * 8 + c] =
            (int)((cb >> 5) * 128 + ((cb >> 2) & 7) * 16 + cq[c] * 4 + (cb & 3));
      }
    } else {
      bkbuf[tid] = bestk;
      out[QOFF + 2 + blockBase + tid] = (float)bestk;
      atomicAdd(&counts[bestk], 1);
    }
  }
  __syncthreads();

  // ---- phase 3b: parallel exact refine (np-order fp32 emulation) ----
  // 8 lanes per gated point, one candidate chain each; identical fp32
  // sequence per candidate as the reference; lex-min (dist, k) select.
  const int ng = gcnt;
  for (int base = 0; base < ng; base += 32) {
    int i = base + (tid >> 3);
    if (i < ng) {
      const int p = glist[i];
      const int c = tid & 7;
      int k = gks[i * 8 + c];
      const float* f = x + (size_t)(blockBase + p) * 64;
      // ||f||^2 in ref order (redundant across the 8 lanes; same loads)
      float r8[8];
#pragma unroll
      for (int j = 0; j < 8; ++j) { float fv = f[j]; r8[j] = __fmul_rn(fv, fv); }
#pragma unroll
      for (int ii = 8; ii < D; ii += 8)
#pragma unroll
        for (int j = 0; j < 8; ++j) {
          float fv = f[ii + j];
          r8[j] = __fadd_rn(r8[j], __fmul_rn(fv, fv));
        }
      float A = __fadd_rn(__fadd_rn(__fadd_rn(r8[0], r8[1]), __fadd_rn(r8[2], r8[3])),
                          __fadd_rn(__fadd_rn(r8[4], r8[5]), __fadd_rn(r8[6], r8[7])));
      // sequential fp32 fma over d ascending (BLAS k-loop order)
      const float* er = Etg + (size_t)k * 64;
      float m = 0.f;
#pragma unroll
      for (int d = 0; d < D; ++d) m = __fmaf_rn(f[d], er[d], m);
      float dist = __fadd_rn(__fsub_rn(A, __fmul_rn(2.f, m)), eC[k]);
      // lex-min (dist, k) across the 8 candidate lanes
#pragma unroll
      for (int off = 4; off >= 1; off >>= 1) {
        float d2 = __shfl_xor(dist, off);
        int k2 = __shfl_xor(k, off);
        if (d2 < dist || (d2 == dist && k2 < k)) { dist = d2; k = k2; }
      }
      if (c == 0) {
        bkbuf[p] = k;
        out[QOFF + 2 + blockBase + p] = (float)k;
        atomicAdd(&counts[k], 1);
      }
    }
  }
  __syncthreads();

  // ---- phase 4: quantized write (gather from Et, coalesced) + loss ----
  const int pp = tid >> 1, half = tid & 1;
  const int bk = bkbuf[pp];
  const float4* et = (const float4*)(Etg + (size_t)bk * 64 + half * 32);
  const float4* xr = (const float4*)(x + (size_t)(blockBase + pp) * 64 + half * 32);
  float4* ov = (float4*)(out + (size_t)(blockBase + pp) * 64 + half * 32);
  float errs = 0.f;
#pragma unroll
  for (int i = 0; i < 8; ++i) {
    float4 qv = et[i];
    float4 xv = xr[i];
    float dx;
    dx = qv.x - xv.x; errs = fmaf(dx, dx, errs);
    dx = qv.y - xv.y; errs = fmaf(dx, dx, errs);
    dx = qv.z - xv.z; errs = fmaf(dx, dx, errs);
    dx = qv.w - xv.w; errs = fmaf(dx, dx, errs);
    ov[i] = qv;
  }
  double de = (double)errs;
#pragma unroll
  for (int off = 32; off > 0; off >>= 1) de += __shfl_down(de, off, 64);
  if (lane == 0) atomicAdd(lossSum, de);

  // ---- phase 5: last block computes loss + perplexity (fused finalize) ----
  __threadfence();  // release my counts/loss atomics
  if (tid == 0) {
    int t = __hip_atomic_fetch_add(done, 1, __ATOMIC_ACQ_REL,
                                   __HIP_MEMORY_SCOPE_AGENT);
    lastFlag = (t == (int)gridDim.x - 1);
  }
  __syncthreads();
  if (lastFlag) {
    double ent = 0.0;
    for (int k = tid; k < K; k += 256) {
      int c = __hip_atomic_load(&counts[k], __ATOMIC_RELAXED,
                                __HIP_MEMORY_SCOPE_AGENT);
      double pp2 = (double)c / (double)NPTS;
      ent += pp2 * log(pp2 + 1e-10);
    }
    double* sh = (double*)topbuf;  // reuse (4KB >= 2KB)
    sh[tid] = ent;
    __syncthreads();
    for (int s = 128; s > 0; s >>= 1) {
      if (tid < s) sh[tid] += sh[tid + s];
      __syncthreads();
    }
    if (tid == 0) {
      unsigned long long lb = __hip_atomic_load((const unsigned long long*)lossSum,
                                                __ATOMIC_RELAXED,
                                                __HIP_MEMORY_SCOPE_AGENT);
      double L = __longlong_as_double(lb);
      // loss = q_latent + 0.25 * e_latent = 1.25 * mean((q - x)^2)
      out[QOFF + 0] = (float)(1.25 * L / (double)((long)NPTS * D));
      out[QOFF + 1] = (float)exp(-sh[0]);  // perplexity
    }
  }
}

extern "C" void kernel_launch(void* const* d_in, const int* in_sizes, int n_in,
                              void* d_out, int out_size, void* d_ws, size_t ws_size,
                              hipStream_t stream) {
  const float* x = (const float*)d_in[0];
  const float* E = (const float*)d_in[1];
  float* out = (float*)d_out;

  char* ws = (char*)d_ws;
  double* lossSum = (double*)(ws + OFF_LOSS);
  int* done = (int*)(ws + OFF_DONE);
  int* counts = (int*)(ws + OFF_CNT);
  float* eC = (float*)(ws + OFF_EC);
  float* eCb = (float*)(ws + OFF_ECB);
  float* Etg = (float*)(ws + OFF_ET);
  unsigned char* stgb = (unsigned char*)(ws + OFF_STG);

  // prep zeroes lossSum/counts/done itself (ws is poisoned before every
  // timed launch); finalize is fused into vq_main's last block.
  vq_prep<<<36, 256, 0, stream>>>(E, eC, eCb, Etg, stgb, lossSum, counts, done);
  vq_main<<<NPTS / 128, 256, 0, stream>>>(x, stgb, eC, eCb, Etg, out,
                                          lossSum, counts, done);
}

// Round 3
// 137.920 us; speedup vs baseline: 1.5075x; 1.5075x over previous
//
#include <hip/hip_runtime.h>
#include <math.h>

// VQ-VAE VectorQuantizer forward (MFMA bf16-split formulation), round N+3.
// Recomposition of measured-good parts after round-2's bundled regression:
//   - vq_main: VERBATIM round-1 version (measured 74.6us): double-buffered
//     global_load_lds pipeline, counted vmcnt(8), per-thread exact refine,
//     no threadfence/ticket, no post-phase-1 sched_barrier.
//   - vq_prep: round-2's 36-block grid (correctness + parallelism proven).
//   - vq_finalize: separate kernel (round-1 structure).
// Round-2 lesson: fused finalize (__threadfence -> per-block L2 writeback,
// WRITE_SIZE +12MB) + pinned prologue cost +95us; never bundle 3 changes.

typedef __attribute__((ext_vector_type(8))) short short8v;
typedef __attribute__((ext_vector_type(4))) float float4v;
typedef unsigned short u16;
typedef unsigned int u32;

constexpr int D = 64;
constexpr int K = 1024;
constexpr int NPTS = 65536;
constexpr long QOFF = (long)NPTS * D;  // 4194304
constexpr float BIAS = 24.0f;
constexpr float GATE = 5e-3f;  // 2*(split 5e-4 + pack 1e-3) + ref err 2e-4 + margin

// ws layout (16B-aligned sections):
constexpr size_t OFF_LOSS = 0;                               // double
constexpr size_t OFF_CNT  = 256;                             // int[1024]
constexpr size_t OFF_EC   = OFF_CNT + 4096;                  // float[1024] ref-order norms
constexpr size_t OFF_ECB  = OFF_EC + 4096;                   // float[1024] norms + BIAS
constexpr size_t OFF_ET   = OFF_ECB + 4096;                  // float[1024*64] E transposed [k][d]
constexpr size_t OFF_STG  = OFF_ET + (size_t)K * D * 4;      // 256KB pre-swizzled staging image

__device__ __forceinline__ float med3(float a, float b, float c) {
  return __builtin_amdgcn_fmed3f(a, b, c);
}
__device__ __forceinline__ u16 bf16rtn(float x) {
  u32 u = __float_as_uint(x);
  return (u16)((u + 0x7fffu + ((u >> 16) & 1u)) >> 16);
}
__device__ __forceinline__ float bf2f(u16 h) {
  return __uint_as_float(((u32)h) << 16);
}
// async global->LDS, 16B per lane; dest must be wave-uniform base + lane*16.
__device__ __forceinline__ void gl_lds16(const void* g, void* l) {
  __builtin_amdgcn_global_load_lds(
      (const __attribute__((address_space(1))) u32*)g,
      (__attribute__((address_space(3))) u32*)l, 16, 0, 0);
}

// ---------------------------------------------------------------------------
// Prep, grid 36 x 256:
//   blocks 0..31 (8192 threads): thread <-> (k, d-group g of 8): Et rows +
//     pre-swizzled -2E bf16 hi/lo staging image.
//   blocks 32..35 (1024 threads): thread <-> k: ref-order ||e_k||^2 (exact
//     sequential fp32 over d ascending), eCb, counts/loss zeroing.
// Staging image layout (matches vq_main's LDS image; staging = contiguous
// 16B-granular copy): chunk = k>>7, r = k&127, 256B rows:
//   bytes [0,128): hi bf16 16B unit at (s*64+q*16) ^ ((r&7)*16); [128,256): lo
//   d = s*32 + q*8 + j  (A-fragment convention of mfma_f32_16x16x32_bf16)
__global__ __launch_bounds__(256) void vq_prep(const float* __restrict__ E,
                                               float* __restrict__ eC,
                                               float* __restrict__ eCb,
                                               float* __restrict__ Et,
                                               unsigned char* __restrict__ stg,
                                               double* __restrict__ lossSum,
                                               int* __restrict__ counts) {
  const int b = blockIdx.x;
  const int tid = threadIdx.x;
  if (b < 32) {
    int gid = b * 256 + tid;
    int k = gid & 1023;        // block covers 256 consecutive k -> coalesced
    int g = gid >> 10;         // d-group 0..7, d = g*8 + j
    float v[8];
#pragma unroll
    for (int j = 0; j < 8; ++j) v[j] = E[(g * 8 + j) * K + k];
    *(float4*)&Et[(size_t)k * 64 + g * 8] = make_float4(v[0], v[1], v[2], v[3]);
    *(float4*)&Et[(size_t)k * 64 + g * 8 + 4] = make_float4(v[4], v[5], v[6], v[7]);
    short8v hv, lv;
#pragma unroll
    for (int j = 0; j < 8; ++j) {
      float m2 = -2.0f * v[j];  // exact
      u16 h = bf16rtn(m2);
      hv[j] = (short)h;
      lv[j] = (short)bf16rtn(m2 - bf2f(h));
    }
    size_t rowb = (size_t)(k >> 7) * 32768 + (size_t)(k & 127) * 256;
    int s = g >> 2, q = g & 3;  // s*32 + q*8 == g*8
    int off = (s * 64 + q * 16) ^ ((k & 7) * 16);
    *(short8v*)&stg[rowb + off] = hv;
    *(short8v*)&stg[rowb + 128 + off] = lv;
  } else {
    int k = (b - 32) * 256 + tid;  // 0..1023
    float c = __fmul_rn(E[k], E[k]);
#pragma unroll
    for (int d = 1; d < D; ++d) {
      float vv = E[d * K + k];
      c = __fadd_rn(c, __fmul_rn(vv, vv));
    }
    eC[k] = c;
    eCb[k] = c + BIAS;
    counts[k] = 0;
    if (k == 0) *lossSum = 0.0;
  }
}

// ---------------------------------------------------------------------------
// VERBATIM round-1 vq_main (measured 74.6us).
__global__ __launch_bounds__(256) void vq_main(const float* __restrict__ x,
                                               const unsigned char* __restrict__ stg,
                                               const float* __restrict__ eC,
                                               const float* __restrict__ eCb,
                                               const float* __restrict__ Etg,
                                               float* __restrict__ out,
                                               double* __restrict__ lossSum,
                                               int* __restrict__ counts) {
  // LDS: double-buffered 32KB chunk images + full eCb + merge buffers = ~74KB
  // -> 2 blocks/CU (grid 512 = 2/CU anyway).
  __shared__ __align__(16) unsigned char sbuf[2][32768];
  __shared__ __align__(16) float ecb[1024];
  __shared__ __align__(16) float topbuf[256 * 4];
  __shared__ int bkbuf[128];

  const int tid = threadIdx.x;
  const int w = tid >> 6;        // wave id: owns point-tiles 2w, 2w+1
  const int lane = tid & 63;
  const int col = lane & 15;     // A: code row; B/C: point col
  const int quad = lane >> 4;    // k-group (A/B), row-group (C)
  const int blockBase = blockIdx.x * 128;
  const float INF = __builtin_inff();

  // ---- phase 0: stage all biased norms once (plain LDS copy) ----
  *(float4*)&ecb[tid * 4] = *(const float4*)&eCb[tid * 4];

  // ---- phase 1: load + split x into B-fragments (register-resident) ----
  short8v Bh[2][2], Bl[2][2];
#pragma unroll
  for (int pt = 0; pt < 2; ++pt) {
    const float* xp = x + (size_t)(blockBase + w * 32 + pt * 16 + col) * 64;
#pragma unroll
    for (int s = 0; s < 2; ++s) {
      const float4* src = (const float4*)(xp + s * 32 + quad * 8);
      float4 a = src[0], b = src[1];
      float xs[8] = {a.x, a.y, a.z, a.w, b.x, b.y, b.z, b.w};
      short8v hf, lf;
#pragma unroll
      for (int j = 0; j < 8; ++j) {
        u16 h = bf16rtn(xs[j]);
        hf[j] = (short)h;
        lf[j] = (short)bf16rtn(xs[j] - bf2f(h));
      }
      Bh[pt][s] = hf;
      Bl[pt][s] = lf;
    }
  }

  // ---- prologue: stage chunks 0 and 1 (8 x 16B per thread per chunk) ----
  {
    const unsigned char* s0 = stg + (size_t)tid * 16;
#pragma unroll
    for (int i = 0; i < 8; ++i)
      gl_lds16(s0 + i * 4096, &sbuf[0][tid * 16 + i * 4096]);
#pragma unroll
    for (int i = 0; i < 8; ++i)
      gl_lds16(s0 + 32768 + i * 4096, &sbuf[1][tid * 16 + i * 4096]);
  }
  // wait chunk0 (8 newest = chunk1 stay in flight); ecb ds_writes visible.
  asm volatile("s_waitcnt vmcnt(8) lgkmcnt(0)" ::: "memory");
  __builtin_amdgcn_s_barrier();
  __builtin_amdgcn_sched_barrier(0);
  asm volatile("" ::: "memory");

  // running top-2 of packed biased distances, per point-tile
  float b1[2] = {INF, INF}, b2[2] = {INF, INF};
  const int swz = (col & 7) * 16;  // read-side XOR swizzle (row&7 == col&7)

  // ---- phase 2: K loop, 8 chunks of 128 codes, double-buffered ----
#pragma unroll 1
  for (int ch = 0; ch < 8; ++ch) {
    unsigned char* bufB = sbuf[ch & 1];
#pragma unroll
    for (int ct = 0; ct < 8; ++ct) {  // 8 code-tiles of 16
      const int rb = ct * 4096 + col * 256;  // row = ct*16+col, 256B rows
      short8v Ah0 = *(const short8v*)&bufB[rb + ((quad * 16) ^ swz)];
      short8v Ah1 = *(const short8v*)&bufB[rb + ((64 + quad * 16) ^ swz)];
      short8v Al0 = *(const short8v*)&bufB[rb + 128 + ((quad * 16) ^ swz)];
      short8v Al1 = *(const short8v*)&bufB[rb + 128 + ((64 + quad * 16) ^ swz)];
      float4v Ci = *(const float4v*)&ecb[ch * 128 + ct * 16 + quad * 4];
#pragma unroll
      for (int pt = 0; pt < 2; ++pt) {
        // split accumulators: two independent 3-deep MFMA chains per pt
        float4v Ca = Ci;
        float4v Cb = {0.f, 0.f, 0.f, 0.f};
        Ca = __builtin_amdgcn_mfma_f32_16x16x32_bf16(Ah0, Bh[pt][0], Ca, 0, 0, 0);
        Cb = __builtin_amdgcn_mfma_f32_16x16x32_bf16(Ah1, Bh[pt][1], Cb, 0, 0, 0);
        Ca = __builtin_amdgcn_mfma_f32_16x16x32_bf16(Al0, Bh[pt][0], Ca, 0, 0, 0);
        Cb = __builtin_amdgcn_mfma_f32_16x16x32_bf16(Al1, Bh[pt][1], Cb, 0, 0, 0);
        Ca = __builtin_amdgcn_mfma_f32_16x16x32_bf16(Ah0, Bl[pt][0], Ca, 0, 0, 0);
        Cb = __builtin_amdgcn_mfma_f32_16x16x32_bf16(Ah1, Bl[pt][1], Cb, 0, 0, 0);
#pragma unroll
        for (int r = 0; r < 4; ++r) {
          float dv = Ca[r] + Cb[r];
          // pack local id (ch:3b | ct:3b | r:2b) into low 8 mantissa bits
          u32 u = (__float_as_uint(dv) & 0xffffff00u) |
                  (u32)(ch * 32 + ct * 4 + r);
          float v = __uint_as_float(u);
          float pb = b1[pt];
          b1[pt] = fminf(pb, v);
          b2[pt] = med3(pb, b2[pt], v);
        }
      }
    }
    // barrier #1: my LDS reads of bufB delivered; everyone done with bufB.
    asm volatile("s_waitcnt lgkmcnt(0)" ::: "memory");
    __builtin_amdgcn_s_barrier();
    __builtin_amdgcn_sched_barrier(0);
    asm volatile("" ::: "memory");
    if (ch < 6) {
      // overwrite bufB with chunk ch+2; chunk ch+1's 8 loads stay in flight.
      const unsigned char* s2 = stg + (size_t)(ch + 2) * 32768 + (size_t)tid * 16;
#pragma unroll
      for (int i = 0; i < 8; ++i)
        gl_lds16(s2 + i * 4096, &bufB[tid * 16 + i * 4096]);
      asm volatile("s_waitcnt vmcnt(8)" ::: "memory");  // ch+1 done, ch+2 in flight
    } else if (ch == 6) {
      asm volatile("s_waitcnt vmcnt(0)" ::: "memory");  // last chunk (7) done
    }
    if (ch < 7) {
      // barrier #2: every wave has confirmed its share of chunk ch+1 landed.
      __builtin_amdgcn_s_barrier();
      __builtin_amdgcn_sched_barrier(0);
      asm volatile("" ::: "memory");
    }
  }

  // ---- phase 3: stash per-lane top-2, merge per point, gate + refine ----
  topbuf[tid * 4 + 0] = b1[0];
  topbuf[tid * 4 + 1] = b2[0];
  topbuf[tid * 4 + 2] = b1[1];
  topbuf[tid * 4 + 3] = b2[1];
  __syncthreads();

  if (tid < 128) {  // one thread per point; tid == point-in-block by construction
    const int mw = tid >> 5, mpt = (tid >> 4) & 1, mcol = tid & 15;
    float cv[8];
    int cq[8];
    float mv0 = INF, mv1 = INF;
    int q0 = 0;
#pragma unroll
    for (int q = 0; q < 4; ++q) {
      int lbase = (mw * 64 + q * 16 + mcol) * 4 + mpt * 2;
#pragma unroll
      for (int j = 0; j < 2; ++j) {
        float v = topbuf[lbase + j];
        cv[q * 2 + j] = v;
        cq[q * 2 + j] = q;
        if (v < mv0) { mv1 = mv0; mv0 = v; q0 = q; }
        else if (v < mv1) { mv1 = v; }
      }
    }
    u32 lb = __float_as_uint(mv0) & 255u;
    int bestk = (int)((lb >> 5) * 128 + ((lb >> 2) & 7) * 16 + q0 * 4 + (lb & 3));

    if (mv1 - mv0 < GATE) {
      // ----- exact emulation of the np reference's fp32 arithmetic -----
      const float* f = x + (size_t)(blockBase + tid) * 64;
      float r8[8];
#pragma unroll
      for (int j = 0; j < 8; ++j) { float fv = f[j]; r8[j] = __fmul_rn(fv, fv); }
#pragma unroll
      for (int i = 8; i < D; i += 8)
#pragma unroll
        for (int j = 0; j < 8; ++j) {
          float fv = f[i + j];
          r8[j] = __fadd_rn(r8[j], __fmul_rn(fv, fv));
        }
      float A = __fadd_rn(__fadd_rn(__fadd_rn(r8[0], r8[1]), __fadd_rn(r8[2], r8[3])),
                          __fadd_rn(__fadd_rn(r8[4], r8[5]), __fadd_rn(r8[6], r8[7])));
      float bd = INF;
      int bkk = K;
#pragma unroll
      for (int c = 0; c < 8; ++c) {
        u32 cb = __float_as_uint(cv[c]) & 255u;
        int k = (int)((cb >> 5) * 128 + ((cb >> 2) & 7) * 16 + cq[c] * 4 + (cb & 3));
        // Et row is d-ascending -> identical fp32 fma sequence, contiguous loads
        const float* er = Etg + (size_t)k * 64;
        float m = 0.f;
#pragma unroll
        for (int d = 0; d < D; ++d) m = __fmaf_rn(f[d], er[d], m);
        float dist = __fadd_rn(__fsub_rn(A, __fmul_rn(2.f, m)), eC[k]);
        bool better = (dist < bd) || (dist == bd && k < bkk);
        bd = better ? dist : bd;
        bkk = better ? k : bkk;
      }
      bestk = bkk;
    }

    bkbuf[tid] = bestk;
    out[QOFF + 2 + blockBase + tid] = (float)bestk;  // index (exact as float)
    atomicAdd(&counts[bestk], 1);
  }
  __syncthreads();

  // ---- phase 4: quantized write (gather from Et, coalesced) + loss ----
  const int pp = tid >> 1, half = tid & 1;
  const int bk = bkbuf[pp];
  const float4* et = (const float4*)(Etg + (size_t)bk * 64 + half * 32);
  const float4* xr = (const float4*)(x + (size_t)(blockBase + pp) * 64 + half * 32);
  float4* ov = (float4*)(out + (size_t)(blockBase + pp) * 64 + half * 32);
  float errs = 0.f;
#pragma unroll
  for (int i = 0; i < 8; ++i) {
    float4 qv = et[i];
    float4 xv = xr[i];
    float dx;
    dx = qv.x - xv.x; errs = fmaf(dx, dx, errs);
    dx = qv.y - xv.y; errs = fmaf(dx, dx, errs);
    dx = qv.z - xv.z; errs = fmaf(dx, dx, errs);
    dx = qv.w - xv.w; errs = fmaf(dx, dx, errs);
    ov[i] = qv;
  }
  double de = (double)errs;
#pragma unroll
  for (int off = 32; off > 0; off >>= 1) de += __shfl_down(de, off, 64);
  if (lane == 0) atomicAdd(lossSum, de);
}

__global__ __launch_bounds__(256) void vq_finalize(const double* __restrict__ lossSum,
                                                   const int* __restrict__ counts,
                                                   float* __restrict__ out) {
  __shared__ double sh[256];
  double ent = 0.0;
  for (int k = threadIdx.x; k < K; k += 256) {
    double pp = (double)counts[k] / (double)NPTS;
    ent += pp * log(pp + 1e-10);
  }
  sh[threadIdx.x] = ent;
  __syncthreads();
  for (int s = 128; s > 0; s >>= 1) {
    if (threadIdx.x < s) sh[threadIdx.x] += sh[threadIdx.x + s];
    __syncthreads();
  }
  if (threadIdx.x == 0) {
    // loss = q_latent + 0.25 * e_latent = 1.25 * mean((q - x)^2)
    out[QOFF + 0] = (float)(1.25 * (*lossSum) / (double)((long)NPTS * D));
    out[QOFF + 1] = (float)exp(-sh[0]);  // perplexity
  }
}

extern "C" void kernel_launch(void* const* d_in, const int* in_sizes, int n_in,
                              void* d_out, int out_size, void* d_ws, size_t ws_size,
                              hipStream_t stream) {
  const float* x = (const float*)d_in[0];
  const float* E = (const float*)d_in[1];
  float* out = (float*)d_out;

  char* ws = (char*)d_ws;
  double* lossSum = (double*)(ws + OFF_LOSS);
  int* counts = (int*)(ws + OFF_CNT);
  float* eC = (float*)(ws + OFF_EC);
  float* eCb = (float*)(ws + OFF_ECB);
  float* Etg = (float*)(ws + OFF_ET);
  unsigned char* stgb = (unsigned char*)(ws + OFF_STG);

  // prep zeroes lossSum/counts itself (ws is poisoned before every timed
  // launch); no memset dispatch needed.
  vq_prep<<<36, 256, 0, stream>>>(E, eC, eCb, Etg, stgb, lossSum, counts);
  vq_main<<<NPTS / 128, 256, 0, stream>>>(x, stgb, eC, eCb, Etg, out,
                                          lossSum, counts);
  vq_finalize<<<1, 256, 0, stream>>>(lossSum, counts, out);
}

// Round 5
// 129.361 us; speedup vs baseline: 1.6072x; 1.0662x over previous
//
#include <hip/hip_runtime.h>
#include <math.h>

// VQ-VAE VectorQuantizer forward (MFMA bf16-split formulation), round N+5.
// R4 lesson: hipLaunchCooperativeKernel breaks the harness's graph capture
// (ExceptionGroup, fallback couldn't recover) — cooperative launch is banned.
// This round: keep the proven 3-dispatch structure (R3, 137.9us) and attack
// vq_main's 16 K-loop sync points (73us wall vs ~18us pipe work):
//   WAVE-PRIVATE PIPELINES — each wave stages all 32 codes of a mini-chunk
//   into its OWN 2x8KB LDS double-buffer and computes only its own 2
//   point-tiles. K-loop has ZERO barriers; per-wave vmcnt(8) pacing only.
//   - stg image is already byte-ordered as 32 contiguous 8KB mini-chunks
//     (prep unchanged, bit-identical image).
//   - LDS 64KB sbuf + 4KB ecb + 4KB topbuf + bkbuf ~= 72.7KB -> 2 blocks/CU.
//   - packed id becomes (ch:5 | ct2:1 | r:2) = 8 bits; decode sites updated;
//     in-lane tie order (ch,ct2,r) still matches ascending k. Merge/refine
//     otherwise verbatim (same 4-quad sources, 256 codes per source, top-2).

typedef __attribute__((ext_vector_type(8))) short short8v;
typedef __attribute__((ext_vector_type(4))) float float4v;
typedef unsigned short u16;
typedef unsigned int u32;

constexpr int D = 64;
constexpr int K = 1024;
constexpr int NPTS = 65536;
constexpr long QOFF = (long)NPTS * D;  // 4194304
constexpr float BIAS = 24.0f;
constexpr float GATE = 5e-3f;  // 2*(split 5e-4 + pack 1e-3) + ref err 2e-4 + margin

// ws layout (16B-aligned sections):
constexpr size_t OFF_LOSS = 0;                               // double
constexpr size_t OFF_CNT  = 256;                             // int[1024]
constexpr size_t OFF_EC   = OFF_CNT + 4096;                  // float[1024] ref-order norms
constexpr size_t OFF_ECB  = OFF_EC + 4096;                   // float[1024] norms + BIAS
constexpr size_t OFF_ET   = OFF_ECB + 4096;                  // float[1024*64] E transposed [k][d]
constexpr size_t OFF_STG  = OFF_ET + (size_t)K * D * 4;      // 256KB pre-swizzled staging image

__device__ __forceinline__ float med3(float a, float b, float c) {
  return __builtin_amdgcn_fmed3f(a, b, c);
}
__device__ __forceinline__ u16 bf16rtn(float x) {
  u32 u = __float_as_uint(x);
  return (u16)((u + 0x7fffu + ((u >> 16) & 1u)) >> 16);
}
__device__ __forceinline__ float bf2f(u16 h) {
  return __uint_as_float(((u32)h) << 16);
}
// async global->LDS, 16B per lane; dest must be wave-uniform base + lane*16.
__device__ __forceinline__ void gl_lds16(const void* g, void* l) {
  __builtin_amdgcn_global_load_lds(
      (const __attribute__((address_space(1))) u32*)g,
      (__attribute__((address_space(3))) u32*)l, 16, 0, 0);
}

// ---------------------------------------------------------------------------
// Prep, grid 36 x 256 (VERBATIM R3 — image bytes unchanged):
//   blocks 0..31: Et rows + pre-swizzled -2E bf16 hi/lo staging image.
//   blocks 32..35: ref-order ||e_k||^2, eCb, counts/loss zeroing.
// Staging image: chunk128 = k>>7, r = k&127, 256B rows:
//   bytes [0,128): hi bf16 16B unit at (s*64+q*16) ^ ((r&7)*16); [128,256): lo
//   d = s*32 + q*8 + j. NOTE: byte offset of code k == k*256, i.e. the image
//   is also 32 contiguous 8KB mini-chunks of 32 codes — used by vq_main.
__global__ __launch_bounds__(256) void vq_prep(const float* __restrict__ E,
                                               float* __restrict__ eC,
                                               float* __restrict__ eCb,
                                               float* __restrict__ Et,
                                               unsigned char* __restrict__ stg,
                                               double* __restrict__ lossSum,
                                               int* __restrict__ counts) {
  const int b = blockIdx.x;
  const int tid = threadIdx.x;
  if (b < 32) {
    int gid = b * 256 + tid;
    int k = gid & 1023;        // block covers 256 consecutive k -> coalesced
    int g = gid >> 10;         // d-group 0..7, d = g*8 + j
    float v[8];
#pragma unroll
    for (int j = 0; j < 8; ++j) v[j] = E[(g * 8 + j) * K + k];
    *(float4*)&Et[(size_t)k * 64 + g * 8] = make_float4(v[0], v[1], v[2], v[3]);
    *(float4*)&Et[(size_t)k * 64 + g * 8 + 4] = make_float4(v[4], v[5], v[6], v[7]);
    short8v hv, lv;
#pragma unroll
    for (int j = 0; j < 8; ++j) {
      float m2 = -2.0f * v[j];  // exact
      u16 h = bf16rtn(m2);
      hv[j] = (short)h;
      lv[j] = (short)bf16rtn(m2 - bf2f(h));
    }
    size_t rowb = (size_t)(k >> 7) * 32768 + (size_t)(k & 127) * 256;
    int s = g >> 2, q = g & 3;  // s*32 + q*8 == g*8
    int off = (s * 64 + q * 16) ^ ((k & 7) * 16);
    *(short8v*)&stg[rowb + off] = hv;
    *(short8v*)&stg[rowb + 128 + off] = lv;
  } else {
    int k = (b - 32) * 256 + tid;  // 0..1023
    float c = __fmul_rn(E[k], E[k]);
#pragma unroll
    for (int d = 1; d < D; ++d) {
      float vv = E[d * K + k];
      c = __fadd_rn(c, __fmul_rn(vv, vv));
    }
    eC[k] = c;
    eCb[k] = c + BIAS;
    counts[k] = 0;
    if (k == 0) *lossSum = 0.0;
  }
}

// ---------------------------------------------------------------------------
__global__ __launch_bounds__(256) void vq_main(const float* __restrict__ x,
                                               const unsigned char* __restrict__ stg,
                                               const float* __restrict__ eC,
                                               const float* __restrict__ eCb,
                                               const float* __restrict__ Etg,
                                               float* __restrict__ out,
                                               double* __restrict__ lossSum,
                                               int* __restrict__ counts) {
  // Wave-private staging: sbuf[wave][buf] 8KB each = 64KB; + ecb 4KB +
  // topbuf 4KB + bkbuf -> ~72.7KB => 2 blocks/CU.
  __shared__ __align__(16) unsigned char sbuf[4][2][8192];
  __shared__ __align__(16) float ecb[1024];
  __shared__ __align__(16) float topbuf[256 * 4];
  __shared__ int bkbuf[128];

  const int tid = threadIdx.x;
  const int w = tid >> 6;        // wave id: owns point-tiles 2w, 2w+1
  const int lane = tid & 63;
  const int col = lane & 15;     // A: code row; B/C: point col
  const int quad = lane >> 4;    // k-group (A/B), row-group (C)
  const int blockBase = blockIdx.x * 128;
  const float INF = __builtin_inff();

  // ---- phase 0: stage all biased norms once (plain LDS copy) ----
  *(float4*)&ecb[tid * 4] = *(const float4*)&eCb[tid * 4];

  // ---- phase 1: load + split x into B-fragments (register-resident) ----
  short8v Bh[2][2], Bl[2][2];
#pragma unroll
  for (int pt = 0; pt < 2; ++pt) {
    const float* xp = x + (size_t)(blockBase + w * 32 + pt * 16 + col) * 64;
#pragma unroll
    for (int s = 0; s < 2; ++s) {
      const float4* src = (const float4*)(xp + s * 32 + quad * 8);
      float4 a = src[0], b = src[1];
      float xs[8] = {a.x, a.y, a.z, a.w, b.x, b.y, b.z, b.w};
      short8v hf, lf;
#pragma unroll
      for (int j = 0; j < 8; ++j) {
        u16 h = bf16rtn(xs[j]);
        hf[j] = (short)h;
        lf[j] = (short)bf16rtn(xs[j] - bf2f(h));
      }
      Bh[pt][s] = hf;
      Bl[pt][s] = lf;
    }
  }

  // ---- prologue: this wave stages mini-chunks 0 and 1 into its own bufs ----
  {
    const unsigned char* s0 = stg + (size_t)lane * 16;
#pragma unroll
    for (int i = 0; i < 8; ++i)
      gl_lds16(s0 + i * 1024, &sbuf[w][0][i * 1024 + lane * 16]);
#pragma unroll
    for (int i = 0; i < 8; ++i)
      gl_lds16(s0 + 8192 + i * 1024, &sbuf[w][1][i * 1024 + lane * 16]);
  }
  // ONE barrier: ecb ds_writes visible to all waves. No vmcnt drain — the
  // 16 staged loads stay in flight (wave-private, paced by vmcnt below).
  asm volatile("s_waitcnt lgkmcnt(0)" ::: "memory");
  __builtin_amdgcn_s_barrier();
  __builtin_amdgcn_sched_barrier(0);
  asm volatile("" ::: "memory");

  // running top-2 of packed biased distances, per point-tile
  float b1[2] = {INF, INF}, b2[2] = {INF, INF};
  const int swz = (col & 7) * 16;  // read-side XOR swizzle (row&7 == col&7)

  // ---- phase 2: K loop, 32 wave-private mini-chunks of 32 codes ----
  // Zero barriers: each wave reads only LDS it staged itself; double-buffer
  // paced by counted vmcnt (issue ch+2, wait ch via vmcnt(8)).
#pragma unroll 1
  for (int ch = 0; ch < 32; ++ch) {
    const unsigned char* bufB = sbuf[w][ch & 1];
    if (ch < 31) {
      asm volatile("s_waitcnt vmcnt(8)" ::: "memory");   // ch landed; ch+1 may fly
    } else {
      asm volatile("s_waitcnt vmcnt(0)" ::: "memory");   // last chunk landed
    }
#pragma unroll
    for (int ct2 = 0; ct2 < 2; ++ct2) {  // 2 code-tiles of 16
      const int rb = ct2 * 4096 + col * 256;  // row = ct2*16+col, 256B rows
      short8v Ah0 = *(const short8v*)&bufB[rb + ((quad * 16) ^ swz)];
      short8v Ah1 = *(const short8v*)&bufB[rb + ((64 + quad * 16) ^ swz)];
      short8v Al0 = *(const short8v*)&bufB[rb + 128 + ((quad * 16) ^ swz)];
      short8v Al1 = *(const short8v*)&bufB[rb + 128 + ((64 + quad * 16) ^ swz)];
      float4v Ci = *(const float4v*)&ecb[ch * 32 + ct2 * 16 + quad * 4];
#pragma unroll
      for (int pt = 0; pt < 2; ++pt) {
        // split accumulators: two independent 3-deep MFMA chains per pt
        float4v Ca = Ci;
        float4v Cb = {0.f, 0.f, 0.f, 0.f};
        Ca = __builtin_amdgcn_mfma_f32_16x16x32_bf16(Ah0, Bh[pt][0], Ca, 0, 0, 0);
        Cb = __builtin_amdgcn_mfma_f32_16x16x32_bf16(Ah1, Bh[pt][1], Cb, 0, 0, 0);
        Ca = __builtin_amdgcn_mfma_f32_16x16x32_bf16(Al0, Bh[pt][0], Ca, 0, 0, 0);
        Cb = __builtin_amdgcn_mfma_f32_16x16x32_bf16(Al1, Bh[pt][1], Cb, 0, 0, 0);
        Ca = __builtin_amdgcn_mfma_f32_16x16x32_bf16(Ah0, Bl[pt][0], Ca, 0, 0, 0);
        Cb = __builtin_amdgcn_mfma_f32_16x16x32_bf16(Ah1, Bl[pt][1], Cb, 0, 0, 0);
#pragma unroll
        for (int r = 0; r < 4; ++r) {
          float dv = Ca[r] + Cb[r];
          // pack local id (ch:5b | ct2:1b | r:2b) into low 8 mantissa bits;
          // (ch,ct2,r) lexicographic == ascending k for fixed quad => ties
          // still resolve toward lower k.
          u32 u = (__float_as_uint(dv) & 0xffffff00u) |
                  (u32)(ch * 8 + ct2 * 4 + r);
          float v = __uint_as_float(u);
          float pb = b1[pt];
          b1[pt] = fminf(pb, v);
          b2[pt] = med3(pb, b2[pt], v);
        }
      }
    }
    // my ds_reads of bufB delivered (wave-local), then overwrite with ch+2.
    asm volatile("s_waitcnt lgkmcnt(0)" ::: "memory");
    if (ch < 30) {
      const unsigned char* s2 = stg + (size_t)(ch + 2) * 8192 + (size_t)lane * 16;
#pragma unroll
      for (int i = 0; i < 8; ++i)
        gl_lds16(s2 + i * 1024, &sbuf[w][ch & 1][i * 1024 + lane * 16]);
    }
  }

  // ---- phase 3: stash per-lane top-2, merge per point, gate + refine ----
  topbuf[tid * 4 + 0] = b1[0];
  topbuf[tid * 4 + 1] = b2[0];
  topbuf[tid * 4 + 2] = b1[1];
  topbuf[tid * 4 + 3] = b2[1];
  __syncthreads();

  if (tid < 128) {  // one thread per point; tid == point-in-block by construction
    const int mw = tid >> 5, mpt = (tid >> 4) & 1, mcol = tid & 15;
    float cv[8];
    int cq[8];
    float mv0 = INF, mv1 = INF;
    int q0 = 0;
#pragma unroll
    for (int q = 0; q < 4; ++q) {
      int lbase = (mw * 64 + q * 16 + mcol) * 4 + mpt * 2;
#pragma unroll
      for (int j = 0; j < 2; ++j) {
        float v = topbuf[lbase + j];
        cv[q * 2 + j] = v;
        cq[q * 2 + j] = q;
        if (v < mv0) { mv1 = mv0; mv0 = v; q0 = q; }
        else if (v < mv1) { mv1 = v; }
      }
    }
    u32 lb = __float_as_uint(mv0) & 255u;
    // id = ch*8 + ct2*4 + r ; k = ch*32 + ct2*16 + quad*4 + r
    int bestk = (int)((lb >> 3) * 32 + ((lb >> 2) & 1) * 16 + q0 * 4 + (lb & 3));

    if (mv1 - mv0 < GATE) {
      // ----- exact emulation of the np reference's fp32 arithmetic -----
      const float* f = x + (size_t)(blockBase + tid) * 64;
      float r8[8];
#pragma unroll
      for (int j = 0; j < 8; ++j) { float fv = f[j]; r8[j] = __fmul_rn(fv, fv); }
#pragma unroll
      for (int i = 8; i < D; i += 8)
#pragma unroll
        for (int j = 0; j < 8; ++j) {
          float fv = f[i + j];
          r8[j] = __fadd_rn(r8[j], __fmul_rn(fv, fv));
        }
      float A = __fadd_rn(__fadd_rn(__fadd_rn(r8[0], r8[1]), __fadd_rn(r8[2], r8[3])),
                          __fadd_rn(__fadd_rn(r8[4], r8[5]), __fadd_rn(r8[6], r8[7])));
      float bd = INF;
      int bkk = K;
#pragma unroll
      for (int c = 0; c < 8; ++c) {
        u32 cb = __float_as_uint(cv[c]) & 255u;
        int k = (int)((cb >> 3) * 32 + ((cb >> 2) & 1) * 16 + cq[c] * 4 + (cb & 3));
        // Et row is d-ascending -> identical fp32 fma sequence, contiguous loads
        const float* er = Etg + (size_t)k * 64;
        float m = 0.f;
#pragma unroll
        for (int d = 0; d < D; ++d) m = __fmaf_rn(f[d], er[d], m);
        float dist = __fadd_rn(__fsub_rn(A, __fmul_rn(2.f, m)), eC[k]);
        bool better = (dist < bd) || (dist == bd && k < bkk);
        bd = better ? dist : bd;
        bkk = better ? k : bkk;
      }
      bestk = bkk;
    }

    bkbuf[tid] = bestk;
    out[QOFF + 2 + blockBase + tid] = (float)bestk;  // index (exact as float)
    atomicAdd(&counts[bestk], 1);
  }
  __syncthreads();

  // ---- phase 4: quantized write (gather from Et, coalesced) + loss ----
  const int pp = tid >> 1, half = tid & 1;
  const int bk = bkbuf[pp];
  const float4* et = (const float4*)(Etg + (size_t)bk * 64 + half * 32);
  const float4* xr = (const float4*)(x + (size_t)(blockBase + pp) * 64 + half * 32);
  float4* ov = (float4*)(out + (size_t)(blockBase + pp) * 64 + half * 32);
  float errs = 0.f;
#pragma unroll
  for (int i = 0; i < 8; ++i) {
    float4 qv = et[i];
    float4 xv = xr[i];
    float dx;
    dx = qv.x - xv.x; errs = fmaf(dx, dx, errs);
    dx = qv.y - xv.y; errs = fmaf(dx, dx, errs);
    dx = qv.z - xv.z; errs = fmaf(dx, dx, errs);
    dx = qv.w - xv.w; errs = fmaf(dx, dx, errs);
    ov[i] = qv;
  }
  double de = (double)errs;
#pragma unroll
  for (int off = 32; off > 0; off >>= 1) de += __shfl_down(de, off, 64);
  if (lane == 0) atomicAdd(lossSum, de);
}

__global__ __launch_bounds__(256) void vq_finalize(const double* __restrict__ lossSum,
                                                   const int* __restrict__ counts,
                                                   float* __restrict__ out) {
  __shared__ double sh[256];
  double ent = 0.0;
  for (int k = threadIdx.x; k < K; k += 256) {
    double pp = (double)counts[k] / (double)NPTS;
    ent += pp * log(pp + 1e-10);
  }
  sh[threadIdx.x] = ent;
  __syncthreads();
  for (int s = 128; s > 0; s >>= 1) {
    if (threadIdx.x < s) sh[threadIdx.x] += sh[threadIdx.x + s];
    __syncthreads();
  }
  if (threadIdx.x == 0) {
    // loss = q_latent + 0.25 * e_latent = 1.25 * mean((q - x)^2)
    out[QOFF + 0] = (float)(1.25 * (*lossSum) / (double)((long)NPTS * D));
    out[QOFF + 1] = (float)exp(-sh[0]);  // perplexity
  }
}

extern "C" void kernel_launch(void* const* d_in, const int* in_sizes, int n_in,
                              void* d_out, int out_size, void* d_ws, size_t ws_size,
                              hipStream_t stream) {
  const float* x = (const float*)d_in[0];
  const float* E = (const float*)d_in[1];
  float* out = (float*)d_out;

  char* ws = (char*)d_ws;
  double* lossSum = (double*)(ws + OFF_LOSS);
  int* counts = (int*)(ws + OFF_CNT);
  float* eC = (float*)(ws + OFF_EC);
  float* eCb = (float*)(ws + OFF_ECB);
  float* Etg = (float*)(ws + OFF_ET);
  unsigned char* stgb = (unsigned char*)(ws + OFF_STG);

  // prep zeroes lossSum/counts itself (ws is poisoned before every timed
  // launch); no memset dispatch needed.
  vq_prep<<<36, 256, 0, stream>>>(E, eC, eCb, Etg, stgb, lossSum, counts);
  vq_main<<<NPTS / 128, 256, 0, stream>>>(x, stgb, eC, eCb, Etg, out,
                                          lossSum, counts);
  vq_finalize<<<1, 256, 0, stream>>>(lossSum, counts, out);
}